// Round 16
// baseline (256.867 us; speedup 1.0000x reference)
//
#include <hip/hip_runtime.h>

typedef unsigned short u16;
typedef __bf16 bf16x8 __attribute__((ext_vector_type(8)));
typedef float f32x16 __attribute__((ext_vector_type(16)));
typedef unsigned short ushort8 __attribute__((ext_vector_type(8)));

// 1/sqrt(65) * log2(e) folded into Q at projection time (exp2 direct in attn)
#define QSCALE2 0.17894429680154087f

__device__ __forceinline__ u16 f2bf(float f) {
  unsigned u = __float_as_uint(f);
  u = (u + 0x7fffu + ((u >> 16) & 1u)) >> 16;
  return (u16)u;
}

__device__ __forceinline__ f32x16 zero16() {
  f32x16 z;
#pragma unroll
  for (int i = 0; i < 16; ++i) z[i] = 0.0f;
  return z;
}

// async global->LDS, 16B per lane; lds dest = base + lane*16 (linear)
__device__ __forceinline__ void gload_lds16(const u16* g, u16* l) {
  __builtin_amdgcn_global_load_lds(
      (const __attribute__((address_space(1))) void*)g,
      (__attribute__((address_space(3))) void*)l, 16, 0, 0);
}

// ---- convert inp (f32) -> xb (bf16) ----
__global__ __launch_bounds__(256) void cvt_x_kernel(const float4* __restrict__ in,
                                                    ushort4* __restrict__ out) {
  int i = blockIdx.x * 256 + threadIdx.x;
  float4 v = in[i];
  ushort4 o;
  o.x = f2bf(v.x); o.y = f2bf(v.y); o.z = f2bf(v.z); o.w = f2bf(v.w);
  out[i] = o;
}

// ---- convert weights -> wtt bf16 [wsel][544][512]; wtt[w][j][k] = w[j][k+4] ----
__global__ __launch_bounds__(256) void cvt_w_kernel(const float* __restrict__ wq,
                                                    const float* __restrict__ wk,
                                                    const float* __restrict__ wv,
                                                    u16* __restrict__ wtt) {
  int id = blockIdx.x * 256 + threadIdx.x;
  int wsel = id / (544 * 512);
  int rem = id - wsel * (544 * 512);
  int j = rem >> 9, k = rem & 511;
  const float* wp = (wsel == 0) ? wq : (wsel == 1) ? wk : wv;
  float v = (j < 520) ? wp[j * 520 + k + 4] : 0.0f;
  wtt[id] = f2bf(v);
}

__global__ __launch_bounds__(256) void zero_kernel(uint4* __restrict__ p, int n) {
  int i = blockIdx.x * 256 + threadIdx.x;
  uint4 z = make_uint4(0u, 0u, 0u, 0u);
  for (; i < n; i += gridDim.x * 256) p[i] = z;
}

// ---- projection GEMM; writes Q row-major, K planar, V planar (repack fused) ----
__global__ __launch_bounds__(256) void proj_kernel(const u16* __restrict__ xb,
                                                   const u16* __restrict__ wtt,
                                                   u16* __restrict__ qb,
                                                   u16* __restrict__ kpl,
                                                   u16* __restrict__ vpl) {
  int tid = threadIdx.x;
  int w = tid >> 6, l = tid & 63, lr = l & 31, lh = l >> 5;
  int m0 = blockIdx.y * 128 + w * 32;
  int g = blockIdx.x;

  const u16* ap = xb + (size_t)(m0 + lr) * 512 + lh * 8;

  f32x16 acc[4];
  const u16* bp[4];
  bool valid[4];
#pragma unroll
  for (int i = 0; i < 4; ++i) {
    int nt = g * 4 + i;
    valid[i] = (nt < 51);
    int ntc = valid[i] ? nt : 50;
    bp[i] = wtt + ((size_t)((ntc / 17) * 544 + (ntc % 17) * 32) + lr) * 512 + lh * 8;
    acc[i] = zero16();
  }

#pragma unroll 4
  for (int s = 0; s < 32; ++s) {
    bf16x8 a = *reinterpret_cast<const bf16x8*>(ap + s * 16);
#pragma unroll
    for (int i = 0; i < 4; ++i) {
      if (valid[i]) {
        bf16x8 b = *reinterpret_cast<const bf16x8*>(bp[i] + s * 16);
        acc[i] = __builtin_amdgcn_mfma_f32_32x32x16_bf16(a, b, acc[i], 0, 0, 0);
      }
    }
  }

#pragma unroll
  for (int i = 0; i < 4; ++i) {
    int nt = g * 4 + i;
    if (nt < 51) {
      int wsel = nt / 17;
      int j = (nt % 17) * 32 + lr;
      if (j < 520) {
        int h = j / 65, dh = j - h * 65;
        if (wsel == 2) {
          // V planar: quartet rows m = m0 + g2*8 + 4lh + e (e=0..3), same kc
#pragma unroll
          for (int g2 = 0; g2 < 4; ++g2) {
            int m = m0 + g2 * 8 + 4 * lh;
            int bb = m >> 11, lrow = m & 2047;
            int bh = bb * 8 + h;
            int kc = lrow >> 3;
            ushort4 vv;
            vv.x = f2bf(acc[i][4 * g2]);
            vv.y = f2bf(acc[i][4 * g2 + 1]);
            vv.z = f2bf(acc[i][4 * g2 + 2]);
            vv.w = f2bf(acc[i][4 * g2 + 3]);
            *reinterpret_cast<ushort4*>(
                &vpl[(((size_t)bh * 256 + kc) * 80 + dh) * 8 + 4 * lh]) = vv;
          }
        } else {
#pragma unroll
          for (int r = 0; r < 16; ++r) {
            int m = m0 + (r & 3) + 8 * (r >> 2) + 4 * lh;
            int bb = m >> 11, lrow = m & 2047;
            int bh = bb * 8 + h;
            if (wsel == 0) {
              qb[((size_t)bh * 2048 + lrow) * 80 + dh] = f2bf(acc[i][r] * QSCALE2);
            } else {
              kpl[(((size_t)bh * 10 + (dh >> 3)) * 2048 + lrow) * 8 + (dh & 7)] = f2bf(acc[i][r]);
            }
          }
        }
      }
    }
  }
}

// ---- fused attention: 2 q-tiles per wave (halved inter-block staging) ----
// grid 256, block 256 (4 waves); wave w handles rows {q0+w*32, q0+128+w*32}.
// 8 blocks/bh -> staging reads halved vs r15. Counted vmcnt + stagger kept.
__global__ __launch_bounds__(256) void attn_kernel(const u16* __restrict__ qb,
                                                   const u16* __restrict__ kpl,
                                                   const u16* __restrict__ vpl,
                                                   float* __restrict__ out,
                                                   float* __restrict__ attn) {
  __shared__ u16 kvbuf[2][10240];   // 2 x 20 KB
  __shared__ u16 plds[4][32][40];   // 10 KB, per-wave P staging (reused A/B)

  int b = blockIdx.x;                        // 0..255
  int bh = (b & 7) + 8 * (b >> 6);           // XCD (b&7) serves bh {c,c+8,c+16,c+24}
  int qblk = (b >> 3) & 7;                   // 8 q-blocks of 256 rows
  int tid = threadIdx.x;
  int w = tid >> 6, l = tid & 63, lr = l & 31, lh = l >> 5;
  int q0 = qblk * 256;
  int qA = q0 + w * 32, qB = q0 + 128 + w * 32;
  int phase = (b * 11) & 31;

  const u16* kbh = kpl + (size_t)bh * 163840;
  const u16* vbh = vpl + (size_t)bh * 163840;

  // Q fragments for both tiles
  bf16x8 qf[2][5];
#pragma unroll
  for (int qt = 0; qt < 2; ++qt) {
    const u16* qptr = qb + ((size_t)bh * 2048 + (qt ? qB : qA) + lr) * 80 + lh * 8;
#pragma unroll
    for (int s = 0; s < 5; ++s)
      qf[qt][s] = *reinterpret_cast<const bf16x8*>(qptr + s * 16);
  }

  // ---------- pass 1: row sums of exp2(S), K tiles of 128 keys ----------
  float sum[2][16];
#pragma unroll
  for (int qt = 0; qt < 2; ++qt)
#pragma unroll
    for (int r2 = 0; r2 < 16; ++r2) sum[qt][r2] = 0.0f;

#define STAGE_K128(kt, bufi)                                                  \
  {                                                                           \
    _Pragma("unroll")                                                         \
    for (int i = 0; i < 5; ++i) {                                             \
      int idx = w + i * 4;                                                    \
      int c = idx >> 1, half = idx & 1;                                       \
      gload_lds16(kbh + (size_t)c * 16384 + (kt) * 1024 + half * 512 + l * 8, \
                  &kvbuf[bufi][idx * 512]);                                   \
    }                                                                         \
  }

  STAGE_K128(0, 0);
  __syncthreads();
  int buf = 0;
  for (int t = 0; t < 16; ++t) {
    if (t < 15) STAGE_K128(t + 1, buf ^ 1);
#pragma unroll
    for (int sub = 0; sub < 4; ++sub) {
#pragma unroll
      for (int qt = 0; qt < 2; ++qt) {
        f32x16 acc = zero16();
#pragma unroll
        for (int s = 0; s < 5; ++s) {
          bf16x8 bk = *reinterpret_cast<const bf16x8*>(
              &kvbuf[buf][((2 * s + lh) * 128 + sub * 32 + lr) * 8]);
          acc = __builtin_amdgcn_mfma_f32_32x32x16_bf16(qf[qt][s], bk, acc, 0, 0, 0);
        }
#pragma unroll
        for (int r2 = 0; r2 < 16; ++r2)
          sum[qt][r2] += __builtin_amdgcn_exp2f(acc[r2]);
      }
    }
    __syncthreads();
    buf ^= 1;
  }

#pragma unroll
  for (int qt = 0; qt < 2; ++qt)
#pragma unroll
    for (int r2 = 0; r2 < 16; ++r2) {
      float s = sum[qt][r2];
#pragma unroll
      for (int d = 1; d < 32; d <<= 1) s += __shfl_xor(s, d);
      sum[qt][r2] = 1.0f / s;
    }

  // ---------- pass 2: recompute S, write attn, PV; (K+V) tiles of 64 keys ----------
#define STAGE_KV64(t64, bufi)                                                 \
  {                                                                           \
    _Pragma("unroll")                                                         \
    for (int i = 0; i < 5; ++i) {                                             \
      int idx = w + i * 4;                                                    \
      const u16* src = (idx < 10)                                             \
          ? kbh + (size_t)idx * 16384 + (t64) * 512 + l * 8                   \
          : vbh + (size_t)(t64) * 5120 + (idx - 10) * 512 + l * 8;            \
      gload_lds16(src, &kvbuf[bufi][idx * 512]);                              \
    }                                                                         \
  }

  f32x16 O[2][3];
#pragma unroll
  for (int qt = 0; qt < 2; ++qt)
#pragma unroll
    for (int n = 0; n < 3; ++n) O[qt][n] = zero16();

  STAGE_KV64(phase, 0);
  __syncthreads();
  buf = 0;
  for (int t = 0; t < 32; ++t) {
    int tt = (t + phase) & 31;
    if (t < 31) STAGE_KV64((tt + 1) & 31, buf ^ 1);
#pragma unroll
    for (int sub = 0; sub < 2; ++sub) {
      int key0 = tt * 64 + sub * 32;
#pragma unroll
      for (int qt = 0; qt < 2; ++qt) {
        float* attn_base = attn + ((size_t)bh * 2048 + (qt ? qB : qA)) * 2048;
        f32x16 acc = zero16();
#pragma unroll
        for (int s = 0; s < 5; ++s) {
          bf16x8 bk = *reinterpret_cast<const bf16x8*>(
              &kvbuf[buf][((2 * s + lh) * 64 + sub * 32 + lr) * 8]);
          acc = __builtin_amdgcn_mfma_f32_32x32x16_bf16(qf[qt][s], bk, acc, 0, 0, 0);
        }
#pragma unroll
        for (int r2 = 0; r2 < 16; ++r2) {
          int row = (r2 & 3) + 8 * (r2 >> 2) + 4 * lh;
          float p = __builtin_amdgcn_exp2f(acc[r2]) * sum[qt][r2];
          __builtin_nontemporal_store(p, &attn_base[(size_t)row * 2048 + key0 + lr]);
          plds[w][row][lr] = f2bf(p);
        }
#pragma unroll
        for (int ks = 0; ks < 2; ++ks) {
          bf16x8 pa = *reinterpret_cast<const bf16x8*>(&plds[w][lr][ks * 16 + lh * 8]);
#pragma unroll
          for (int n = 0; n < 3; ++n) {
            bf16x8 bv = *reinterpret_cast<const bf16x8*>(
                &kvbuf[buf][5120 + ((sub * 4 + 2 * ks + lh) * 80 + n * 32 + lr) * 8]);
            O[qt][n] = __builtin_amdgcn_mfma_f32_32x32x16_bf16(pa, bv, O[qt][n], 0, 0, 0);
          }
        }
      }
    }
    // per tile: 20 loads + 64 stores issued. vmcnt(48) retires loads + older
    // stores, leaves 48 stores in flight across the barrier.
    asm volatile("s_waitcnt vmcnt(48)" ::: "memory");
    __builtin_amdgcn_s_barrier();
    buf ^= 1;
  }

  // ---- direct out write: c = h*65 + d - 4
  int bb = bh >> 3, h = bh & 7;
#pragma unroll
  for (int qt = 0; qt < 2; ++qt) {
    int qx = qt ? qB : qA;
#pragma unroll
    for (int n = 0; n < 3; ++n) {
      int d = n * 32 + lr;
      int cc = h * 65 + d - 4;
      if (d < 65 && cc >= 0 && cc < 512) {
#pragma unroll
        for (int r2 = 0; r2 < 16; ++r2) {
          int row = (r2 & 3) + 8 * (r2 >> 2) + 4 * lh;
          out[((size_t)bb * 2048 + qx + row) * 512 + cc] = O[qt][n][r2];
        }
      }
    }
  }
}

extern "C" void kernel_launch(void* const* d_in, const int* in_sizes, int n_in,
                              void* d_out, int out_size, void* d_ws, size_t ws_size,
                              hipStream_t stream) {
  (void)in_sizes; (void)n_in; (void)out_size; (void)ws_size;
  const float* inp = (const float*)d_in[0];
  const float* wq  = (const float*)d_in[1];
  const float* wk  = (const float*)d_in[2];
  const float* wv  = (const float*)d_in[3];

  char* ws = (char*)d_ws;
  u16* xb  = (u16*)(ws + 0);                        // 8,388,608
  u16* wtt = (u16*)(ws + 8388608);                  // 1,671,168
  u16* qb  = (u16*)(ws + 10059776);                 // 10,485,760
  u16* kpl = (u16*)(ws + 20545536);                 // 10,485,760 (planar K)
  u16* vpl = (u16*)(ws + 31031296);                 // 10,485,760 (planar V)

  float* out  = (float*)d_out;
  float* attn = out + (size_t)4 * 2048 * 512;

  cvt_x_kernel<<<4096, 256, 0, stream>>>((const float4*)inp, (ushort4*)xb);
  cvt_w_kernel<<<3264, 256, 0, stream>>>(wq, wk, wv, wtt);
  // zero qb only: Q pads must be 0 (K/V pad garbage is annihilated by q-pad zeros
  // in QK and discarded rows/cols in PV; 0xAA poison is finite bf16)
  zero_kernel<<<640, 256, 0, stream>>>((uint4*)qb, 655360);
  proj_kernel<<<dim3(13, 64), 256, 0, stream>>>(xb, wtt, qb, kpl, vpl);
  attn_kernel<<<256, 256, 0, stream>>>(qb, kpl, vpl, out, attn);
}

// Round 17
// 242.222 us; speedup vs baseline: 1.0605x; 1.0605x over previous
//
#include <hip/hip_runtime.h>

typedef unsigned short u16;
typedef __bf16 bf16x8 __attribute__((ext_vector_type(8)));
typedef float f32x16 __attribute__((ext_vector_type(16)));
typedef unsigned short ushort8 __attribute__((ext_vector_type(8)));

// 1/sqrt(65) * log2(e) folded into Q at projection time (exp2 direct in attn)
#define QSCALE2 0.17894429680154087f

__device__ __forceinline__ u16 f2bf(float f) {
  unsigned u = __float_as_uint(f);
  u = (u + 0x7fffu + ((u >> 16) & 1u)) >> 16;
  return (u16)u;
}

__device__ __forceinline__ f32x16 zero16() {
  f32x16 z;
#pragma unroll
  for (int i = 0; i < 16; ++i) z[i] = 0.0f;
  return z;
}

// async global->LDS, 16B per lane; lds dest = base + lane*16 (linear)
__device__ __forceinline__ void gload_lds16(const u16* g, u16* l) {
  __builtin_amdgcn_global_load_lds(
      (const __attribute__((address_space(1))) void*)g,
      (__attribute__((address_space(3))) void*)l, 16, 0, 0);
}

// ---- convert inp (f32) -> xb (bf16) ----
__global__ __launch_bounds__(256) void cvt_x_kernel(const float4* __restrict__ in,
                                                    ushort4* __restrict__ out) {
  int i = blockIdx.x * 256 + threadIdx.x;
  float4 v = in[i];
  ushort4 o;
  o.x = f2bf(v.x); o.y = f2bf(v.y); o.z = f2bf(v.z); o.w = f2bf(v.w);
  out[i] = o;
}

// ---- convert weights -> wtt bf16 [wsel][544][512]; wtt[w][j][k] = w[j][k+4] ----
__global__ __launch_bounds__(256) void cvt_w_kernel(const float* __restrict__ wq,
                                                    const float* __restrict__ wk,
                                                    const float* __restrict__ wv,
                                                    u16* __restrict__ wtt) {
  int id = blockIdx.x * 256 + threadIdx.x;
  int wsel = id / (544 * 512);
  int rem = id - wsel * (544 * 512);
  int j = rem >> 9, k = rem & 511;
  const float* wp = (wsel == 0) ? wq : (wsel == 1) ? wk : wv;
  float v = (j < 520) ? wp[j * 520 + k + 4] : 0.0f;
  wtt[id] = f2bf(v);
}

__global__ __launch_bounds__(256) void zero_kernel(uint4* __restrict__ p, int n) {
  int i = blockIdx.x * 256 + threadIdx.x;
  uint4 z = make_uint4(0u, 0u, 0u, 0u);
  for (; i < n; i += gridDim.x * 256) p[i] = z;
}

// ---- projection GEMM; writes Q row-major, K planar, V planar (repack fused) ----
// kpl[((bh*10 + dh/8)*2048 + key)*8 + dh%8]
// vpl[((bh*256 + key/8)*80 + dh)*8 + key%8]  (quartet ushort4 stores)
__global__ __launch_bounds__(256) void proj_kernel(const u16* __restrict__ xb,
                                                   const u16* __restrict__ wtt,
                                                   u16* __restrict__ qb,
                                                   u16* __restrict__ kpl,
                                                   u16* __restrict__ vpl) {
  int tid = threadIdx.x;
  int w = tid >> 6, l = tid & 63, lr = l & 31, lh = l >> 5;
  int m0 = blockIdx.y * 128 + w * 32;
  int g = blockIdx.x;

  const u16* ap = xb + (size_t)(m0 + lr) * 512 + lh * 8;

  f32x16 acc[4];
  const u16* bp[4];
  bool valid[4];
#pragma unroll
  for (int i = 0; i < 4; ++i) {
    int nt = g * 4 + i;
    valid[i] = (nt < 51);
    int ntc = valid[i] ? nt : 50;
    bp[i] = wtt + ((size_t)((ntc / 17) * 544 + (ntc % 17) * 32) + lr) * 512 + lh * 8;
    acc[i] = zero16();
  }

#pragma unroll 4
  for (int s = 0; s < 32; ++s) {
    bf16x8 a = *reinterpret_cast<const bf16x8*>(ap + s * 16);
#pragma unroll
    for (int i = 0; i < 4; ++i) {
      if (valid[i]) {
        bf16x8 b = *reinterpret_cast<const bf16x8*>(bp[i] + s * 16);
        acc[i] = __builtin_amdgcn_mfma_f32_32x32x16_bf16(a, b, acc[i], 0, 0, 0);
      }
    }
  }

#pragma unroll
  for (int i = 0; i < 4; ++i) {
    int nt = g * 4 + i;
    if (nt < 51) {
      int wsel = nt / 17;
      int j = (nt % 17) * 32 + lr;
      if (j < 520) {
        int h = j / 65, dh = j - h * 65;
        if (wsel == 2) {
          // V planar: quartet rows m = m0 + g2*8 + 4lh + e (e=0..3), same kc
#pragma unroll
          for (int g2 = 0; g2 < 4; ++g2) {
            int m = m0 + g2 * 8 + 4 * lh;
            int bb = m >> 11, lrow = m & 2047;
            int bh = bb * 8 + h;
            int kc = lrow >> 3;
            ushort4 vv;
            vv.x = f2bf(acc[i][4 * g2]);
            vv.y = f2bf(acc[i][4 * g2 + 1]);
            vv.z = f2bf(acc[i][4 * g2 + 2]);
            vv.w = f2bf(acc[i][4 * g2 + 3]);
            *reinterpret_cast<ushort4*>(
                &vpl[(((size_t)bh * 256 + kc) * 80 + dh) * 8 + 4 * lh]) = vv;
          }
        } else {
#pragma unroll
          for (int r = 0; r < 16; ++r) {
            int m = m0 + (r & 3) + 8 * (r >> 2) + 4 * lh;
            int bb = m >> 11, lrow = m & 2047;
            int bh = bb * 8 + h;
            if (wsel == 0) {
              qb[((size_t)bh * 2048 + lrow) * 80 + dh] = f2bf(acc[i][r] * QSCALE2);
            } else {
              kpl[(((size_t)bh * 10 + (dh >> 3)) * 2048 + lrow) * 8 + (dh & 7)] = f2bf(acc[i][r]);
            }
          }
        }
      }
    }
  }
}

// ---- fused attention (r15 structure — session best: 243.4 us) ----
// grid 512, block 256 (4 waves => 128 q-rows), ~3 blocks/CU.
// Pass1: K dbuf tiles of 128 keys. Pass2: (K+V) dbuf tiles of 64 keys,
// counted vmcnt + raw s_barrier + per-block key-phase stagger; NT attn stores.
__global__ __launch_bounds__(256, 2) void attn_kernel(const u16* __restrict__ qb,
                                                      const u16* __restrict__ kpl,
                                                      const u16* __restrict__ vpl,
                                                      float* __restrict__ out,
                                                      float* __restrict__ attn) {
  __shared__ u16 kvbuf[2][10240];   // 2 x 20 KB
  __shared__ u16 plds[4][32][40];   // 10 KB, per-wave P staging

  int b = blockIdx.x;                        // 0..511
  int bh = (b & 7) + 8 * (b >> 7);           // XCD (b&7) serves bh {c,c+8,c+16,c+24}
  int qblk = (b >> 3) & 15;                  // 16 q-blocks of 128 rows
  int tid = threadIdx.x;
  int w = tid >> 6, l = tid & 63, lr = l & 31, lh = l >> 5;
  int q0 = qblk * 128 + w * 32;
  int phase = (b * 11) & 31;                 // pass-2 key-tile phase stagger

  const u16* kbh = kpl + (size_t)bh * 163840;   // 10 chunks * 2048 keys * 8
  const u16* vbh = vpl + (size_t)bh * 163840;   // 256 kc * 80 d * 8

  // Q fragments (rows q0+lr, head-dim 16s+8lh+e), held in regs across both passes
  const u16* qptr = qb + ((size_t)bh * 2048 + q0 + lr) * 80 + lh * 8;
  bf16x8 qf[5];
#pragma unroll
  for (int s = 0; s < 5; ++s) qf[s] = *reinterpret_cast<const bf16x8*>(qptr + s * 16);

  // ---------- pass 1: row sums of exp2(S), K tiles of 128 keys ----------
  float sum[16];
#pragma unroll
  for (int r2 = 0; r2 < 16; ++r2) sum[r2] = 0.0f;

  // stage K tile kt into kvbuf[buf]: 20 loads (idx = w+4i), layout [c][128][8]
#define STAGE_K128(kt, bufi)                                                  \
  {                                                                           \
    _Pragma("unroll")                                                         \
    for (int i = 0; i < 5; ++i) {                                             \
      int idx = w + i * 4;                                                    \
      int c = idx >> 1, half = idx & 1;                                       \
      gload_lds16(kbh + (size_t)c * 16384 + (kt) * 1024 + half * 512 + l * 8, \
                  &kvbuf[bufi][idx * 512]);                                   \
    }                                                                         \
  }

  STAGE_K128(0, 0);
  __syncthreads();
  int buf = 0;
  for (int t = 0; t < 16; ++t) {
    if (t < 15) STAGE_K128(t + 1, buf ^ 1);
#pragma unroll
    for (int sub = 0; sub < 4; ++sub) {
      f32x16 acc = zero16();
#pragma unroll
      for (int s = 0; s < 5; ++s) {
        bf16x8 bk = *reinterpret_cast<const bf16x8*>(
            &kvbuf[buf][((2 * s + lh) * 128 + sub * 32 + lr) * 8]);
        acc = __builtin_amdgcn_mfma_f32_32x32x16_bf16(qf[s], bk, acc, 0, 0, 0);
      }
#pragma unroll
      for (int r2 = 0; r2 < 16; ++r2)
        sum[r2] += __builtin_amdgcn_exp2f(acc[r2]);
    }
    __syncthreads();
    buf ^= 1;
  }

#pragma unroll
  for (int r2 = 0; r2 < 16; ++r2) {
    float s = sum[r2];
#pragma unroll
    for (int d = 1; d < 32; d <<= 1) s += __shfl_xor(s, d);
    sum[r2] = 1.0f / s;
  }

  // ---------- pass 2: recompute S, write attn, PV; (K+V) tiles of 64 keys ----------
  // stage pair tile t64: K [c][64][8] at 0..5119, V [kc8][80][8] at 5120..10239
#define STAGE_KV64(t64, bufi)                                                 \
  {                                                                           \
    _Pragma("unroll")                                                         \
    for (int i = 0; i < 5; ++i) {                                             \
      int idx = w + i * 4;                                                    \
      const u16* src = (idx < 10)                                             \
          ? kbh + (size_t)idx * 16384 + (t64) * 512 + l * 8                   \
          : vbh + (size_t)(t64) * 5120 + (idx - 10) * 512 + l * 8;            \
      gload_lds16(src, &kvbuf[bufi][idx * 512]);                              \
    }                                                                         \
  }

  f32x16 O[3];
#pragma unroll
  for (int n = 0; n < 3; ++n) O[n] = zero16();

  float* attn_base = attn + ((size_t)bh * 2048 + q0) * 2048;

  STAGE_KV64(phase, 0);
  __syncthreads();
  buf = 0;
  for (int t = 0; t < 32; ++t) {
    int tt = (t + phase) & 31;
    if (t < 31) STAGE_KV64((tt + 1) & 31, buf ^ 1);
#pragma unroll
    for (int sub = 0; sub < 2; ++sub) {
      int key0 = tt * 64 + sub * 32;
      f32x16 acc = zero16();
#pragma unroll
      for (int s = 0; s < 5; ++s) {
        bf16x8 bk = *reinterpret_cast<const bf16x8*>(
            &kvbuf[buf][((2 * s + lh) * 64 + sub * 32 + lr) * 8]);
        acc = __builtin_amdgcn_mfma_f32_32x32x16_bf16(qf[s], bk, acc, 0, 0, 0);
      }
#pragma unroll
      for (int r2 = 0; r2 < 16; ++r2) {
        int row = (r2 & 3) + 8 * (r2 >> 2) + 4 * lh;
        float p = __builtin_amdgcn_exp2f(acc[r2]) * sum[r2];
        __builtin_nontemporal_store(p, &attn_base[(size_t)row * 2048 + key0 + lr]);
        plds[w][row][lr] = f2bf(p);
      }
#pragma unroll
      for (int ks = 0; ks < 2; ++ks) {
        bf16x8 pa = *reinterpret_cast<const bf16x8*>(&plds[w][lr][ks * 16 + lh * 8]);
#pragma unroll
        for (int n = 0; n < 3; ++n) {
          bf16x8 bv = *reinterpret_cast<const bf16x8*>(
              &kvbuf[buf][5120 + ((sub * 4 + 2 * ks + lh) * 80 + n * 32 + lr) * 8]);
          O[n] = __builtin_amdgcn_mfma_f32_32x32x16_bf16(pa, bv, O[n], 0, 0, 0);
        }
      }
    }
    // Counted wait: issue order this iter = [20 prefetch loads][32 attn stores].
    // Waiting to <=32 outstanding retires prior stores + the 20 loads (in-order
    // retirement), but leaves THIS tile's 32 stores in flight across the barrier.
    asm volatile("s_waitcnt vmcnt(32)" ::: "memory");
    __builtin_amdgcn_s_barrier();
    buf ^= 1;
  }

  // ---- direct out write: c = h*65 + d - 4
  int bb = bh >> 3, h = bh & 7;
#pragma unroll
  for (int n = 0; n < 3; ++n) {
    int d = n * 32 + lr;
    int cc = h * 65 + d - 4;
    if (d < 65 && cc >= 0 && cc < 512) {
#pragma unroll
      for (int r2 = 0; r2 < 16; ++r2) {
        int row = (r2 & 3) + 8 * (r2 >> 2) + 4 * lh;
        out[((size_t)bb * 2048 + q0 + row) * 512 + cc] = O[n][r2];
      }
    }
  }
}

extern "C" void kernel_launch(void* const* d_in, const int* in_sizes, int n_in,
                              void* d_out, int out_size, void* d_ws, size_t ws_size,
                              hipStream_t stream) {
  (void)in_sizes; (void)n_in; (void)out_size; (void)ws_size;
  const float* inp = (const float*)d_in[0];
  const float* wq  = (const float*)d_in[1];
  const float* wk  = (const float*)d_in[2];
  const float* wv  = (const float*)d_in[3];

  char* ws = (char*)d_ws;
  u16* xb  = (u16*)(ws + 0);                        // 8,388,608
  u16* wtt = (u16*)(ws + 8388608);                  // 1,671,168
  u16* qb  = (u16*)(ws + 10059776);                 // 10,485,760
  u16* kpl = (u16*)(ws + 20545536);                 // 10,485,760 (planar K)
  u16* vpl = (u16*)(ws + 31031296);                 // 10,485,760 (planar V)

  float* out  = (float*)d_out;
  float* attn = out + (size_t)4 * 2048 * 512;

  cvt_x_kernel<<<4096, 256, 0, stream>>>((const float4*)inp, (ushort4*)xb);
  cvt_w_kernel<<<3264, 256, 0, stream>>>(wq, wk, wv, wtt);
  // zero qb only: Q pads must be 0 (K/V pad garbage is annihilated by q-pad zeros
  // in QK and discarded rows/cols in PV; 0xAA poison is finite bf16)
  zero_kernel<<<640, 256, 0, stream>>>((uint4*)qb, 655360);
  proj_kernel<<<dim3(13, 64), 256, 0, stream>>>(xb, wtt, qb, kpl, vpl);
  attn_kernel<<<512, 256, 0, stream>>>(qb, kpl, vpl, out, attn);
}